// Round 13
// baseline (4762.472 us; speedup 1.0000x reference)
//
#include <hip/hip_runtime.h>
#include <stdint.h>

// ---------------- types / helpers ----------------
typedef short bf16x8 __attribute__((ext_vector_type(8)));
typedef float f32x4  __attribute__((ext_vector_type(4)));

__device__ static inline unsigned short f2bf(float v){
  unsigned x = __float_as_uint(v);
  unsigned r = (x + 0x7fffu + ((x >> 16) & 1u)) >> 16;
  return (unsigned short)r;
}

__device__ static inline f32x4 mfma16(bf16x8 a, bf16x8 b, f32x4 c){
  return __builtin_amdgcn_mfma_f32_16x16x32_bf16(a, b, c, 0, 0, 0);
}

// Panel (fragment-major) layout: element (r, k) of a [R][K] bf16 matrix lives at
//   idx = (r>>4)*(K/32)*512 + (k>>5)*512 + ((k>>3)&3)*128 + (r&15)*8 + (k&7)
// so one mfma fragment (16 rows x 32 k) = 64 lanes x 16B contiguous (lane l -> l*16B).

// ---------------- prep: weight bf16 round + gate-interleave + panelize ----------------
// gate row r = 4*u + g  <-  src row g*1024 + u   (g: 0=i,1=f,2=g,3=o)
__global__ void k_prep_w(const float* __restrict__ Whh0,
                         const float* __restrict__ Wih1, const float* __restrict__ Whh1,
                         unsigned short* __restrict__ W0p, unsigned short* __restrict__ W1p)
{
  const long n0 = (long)4096 * 1024;
  const long n1 = (long)4096 * 2048;
  long stride = (long)gridDim.x * blockDim.x;
  for (long idx = (long)blockIdx.x * blockDim.x + threadIdx.x; idx < n0 + n1; idx += stride){
    if (idx < n0){
      int i = (int)idx;
      int r = i >> 10, k = i & 1023;
      int u = r >> 2, g = r & 3;
      float v = Whh0[(size_t)(g * 1024 + u) * 1024 + k];
      size_t d = (size_t)(r >> 4) * 16384 + ((size_t)(k >> 5) << 9)
               + (((k >> 3) & 3) << 7) + ((r & 15) << 3) + (k & 7);
      W0p[d] = f2bf(v);
    } else {
      long i = idx - n0;
      int r = (int)(i >> 11), k = (int)(i & 2047);
      int u = r >> 2, g = r & 3;
      int srow = g * 1024 + u;
      float v = (k < 1024) ? Wih1[(size_t)srow * 1024 + k]
                           : Whh1[(size_t)srow * 1024 + (k - 1024)];
      size_t d = (size_t)(r >> 4) * 32768 + ((size_t)(k >> 5) << 9)
               + (((k >> 3) & 3) << 7) + ((r & 15) << 3) + (k & 7);
      W1p[d] = f2bf(v);
    }
  }
}

// ---------------- prep: x-proj+bias (reordered), b1r, zero states, init out ----------------
__global__ void k_prep_misc(const float* __restrict__ x, const float* __restrict__ Wih0,
                            const float* __restrict__ bih0, const float* __restrict__ bhh0,
                            const float* __restrict__ bih1, const float* __restrict__ bhh1,
                            const float* __restrict__ bfc,
                            float* __restrict__ xb0, float* __restrict__ b1r,
                            unsigned short* __restrict__ XAp,
                            float* __restrict__ c0, float* __restrict__ c1,
                            float* __restrict__ out)
{
  const long NXB = (long)512 * 4096;
  const long NXA = (long)2 * 512 * 2048;
  const long NC  = (long)512 * 1024;
  const long NO  = (long)512 * 106 * 2;
  const long total = NXB + 4096 + NXA + 2 * NC + NO;
  long stride = (long)gridDim.x * blockDim.x;
  for (long idx = (long)blockIdx.x * blockDim.x + threadIdx.x; idx < total; idx += stride){
    long t = idx;
    if (t < NXB){
      int m = (int)(t >> 12), c = (int)(t & 4095);
      int u = c >> 2, g = c & 3;
      int row = g * 1024 + u;
      xb0[t] = x[m * 2 + 0] * Wih0[row * 2 + 0] + x[m * 2 + 1] * Wih0[row * 2 + 1]
             + bih0[row] + bhh0[row];
      continue;
    }
    t -= NXB;
    if (t < 4096){
      int c = (int)t; int u = c >> 2, g = c & 3; int row = g * 1024 + u;
      b1r[c] = bih1[row] + bhh1[row]; continue;
    }
    t -= 4096;
    if (t < NXA){ XAp[t] = 0; continue; } t -= NXA;   // zeros are layout-independent
    if (t < NC){ c0[t] = 0.f; continue; } t -= NC;
    if (t < NC){ c1[t] = 0.f; continue; } t -= NC;
    out[t] = bfc[t & 1];
  }
}

// ---------------- merged step kernel: LDS-free GEMM + LSTM pointwise (+FC) ----------------
// Both operands panelized -> every fragment load is one coalesced global_load_dwordx4
// (base + lane*16B). No staging, no in-loop barriers; LDS holds only the gate buffer.
// mode: 0 = merged (512 blocks: [0,256)=L1, [256,512)=L0), 1 = L0-only, 2 = L1-only.
// Per block: BM=64, BN=128, 8 waves (2x4), wave tile 32x32; 2 blocks/CU in merged mode.
__global__ __launch_bounds__(512, 4) void k_lstm_step(
  const unsigned short* __restrict__ XAr,   // panelized [512/16 rowgroups][2048/32 panels][512]
  unsigned short* __restrict__ XAw,
  const unsigned short* __restrict__ W0, const unsigned short* __restrict__ W1,
  const float* __restrict__ xb0, const float* __restrict__ b1r,
  float* __restrict__ c0, float* __restrict__ c1,
  const float* __restrict__ Wfc, float* __restrict__ out,
  int tstep, int mode)
{
  __shared__ float gl[64 * 129];            // gate buffer only (33KB)
  const int tid = threadIdx.x;
  const int wid = tid >> 6, lane = tid & 63;

  int L = blockIdx.x;
  bool isL1;
  if (mode == 0){ isL1 = (L < 256); L &= 255; }
  else          { isL1 = (mode == 2); }

  const unsigned short* Whi = isL1 ? W1 : W0;
  float*               cbuf = isL1 ? c1 : c0;
  const int              NS = isL1 ? 32 : 16;
  const size_t         RGSW = isL1 ? 32768 : 16384;   // W rowgroup stride (elems)

  // XCD-grouped mapping: 32 blocks per XCD = 4 N-tiles x 8 M-tiles (per half, bijective)
  int xc = L & 7, j = L >> 3;
  int ntile = xc * 4 + (j & 3);
  int mtile = j >> 2;
  int m0 = mtile * 64, n0 = ntile * 128;
  int wm = wid >> 2, wn = wid & 3;

  // fragment base pointers (advance by panel index inside the loop)
  const unsigned short* pA0 = XAr + (size_t)((m0 + wm * 32     ) >> 4) * 32768 + lane * 8;
  const unsigned short* pA1 = XAr + (size_t)((m0 + wm * 32 + 16) >> 4) * 32768 + lane * 8;
  const unsigned short* pB0 = Whi + (size_t)((n0 + wn * 32     ) >> 4) * RGSW  + lane * 8;
  const unsigned short* pB1 = Whi + (size_t)((n0 + wn * 32 + 16) >> 4) * RGSW  + lane * 8;

  f32x4 acc[2][2];
  #pragma unroll
  for (int a = 0; a < 2; a++)
    #pragma unroll
    for (int b = 0; b < 2; b++)
      acc[a][b] = (f32x4){0.f, 0.f, 0.f, 0.f};

  #pragma unroll 4
  for (int s = 0; s < NS; s++){
    int off = s << 10;                      // two 512-elem panels per K-step (BK=64)
    bf16x8 a00 = *(const bf16x8*)(pA0 + off);
    bf16x8 a10 = *(const bf16x8*)(pA1 + off);
    bf16x8 b00 = *(const bf16x8*)(pB0 + off);
    bf16x8 b10 = *(const bf16x8*)(pB1 + off);
    bf16x8 a01 = *(const bf16x8*)(pA0 + off + 512);
    bf16x8 a11 = *(const bf16x8*)(pA1 + off + 512);
    bf16x8 b01 = *(const bf16x8*)(pB0 + off + 512);
    bf16x8 b11 = *(const bf16x8*)(pB1 + off + 512);
    acc[0][0] = mfma16(a00, b00, acc[0][0]);
    acc[0][1] = mfma16(a00, b10, acc[0][1]);
    acc[1][0] = mfma16(a10, b00, acc[1][0]);
    acc[1][1] = mfma16(a10, b10, acc[1][1]);
    acc[0][0] = mfma16(a01, b01, acc[0][0]);
    acc[0][1] = mfma16(a01, b11, acc[0][1]);
    acc[1][0] = mfma16(a11, b01, acc[1][0]);
    acc[1][1] = mfma16(a11, b11, acc[1][1]);
  }

  // ---------- epilogue: acc -> LDS gates [64][129], then pointwise LSTM ----------
  #pragma unroll
  for (int fm = 0; fm < 2; fm++)
    #pragma unroll
    for (int fn = 0; fn < 2; fn++)
      #pragma unroll
      for (int r = 0; r < 4; r++){
        int row = wm * 32 + fm * 16 + ((lane >> 4) << 2) + r;
        int col = wn * 32 + fn * 16 + (lane & 15);
        gl[row * 129 + col] = acc[fm][fn][r];
      }
  __syncthreads();

  if (tid < 256){
    int row = tid >> 2;                     // 0..63
    int oct = tid & 3;                      // 0..3 (8-unit octet)
    int gm  = m0 + row;
    int gu0 = (n0 >> 2) + oct * 8;          // first global unit of this octet
    const float* grow = gl + row * 129 + oct * 32;
    const float* av   = isL1 ? (b1r + n0 + oct * 32)
                             : (xb0 + (size_t)gm * 4096 + n0 + oct * 32);
    float p0 = 0.f, p1 = 0.f;
    bf16x8 hv;
    #pragma unroll
    for (int jj = 0; jj < 8; jj++){
      float gi = grow[jj * 4 + 0] + av[jj * 4 + 0];
      float gf = grow[jj * 4 + 1] + av[jj * 4 + 1];
      float gg = grow[jj * 4 + 2] + av[jj * 4 + 2];
      float go = grow[jj * 4 + 3] + av[jj * 4 + 3];
      float ii = 1.f / (1.f + expf(-gi));
      float ff = 1.f / (1.f + expf(-gf));
      float g2 = tanhf(gg);
      float oo = 1.f / (1.f + expf(-go));
      size_t ci = ((size_t)gm << 10) + gu0 + jj;
      float c = ff * cbuf[ci] + ii * g2;
      cbuf[ci] = c;
      float h = oo * tanhf(c);
      hv[jj] = (short)f2bf(h);
      if (isL1){
        p0 += h * Wfc[gu0 + jj];
        p1 += h * Wfc[1024 + gu0 + jj];
      }
    }
    // panelized h-write: 8 consecutive k-cols = one 16B store
    int col0 = gu0 + (isL1 ? 1024 : 0);
    size_t d = (size_t)(gm >> 4) * 32768 + ((size_t)(col0 >> 5) << 9)
             + (((col0 >> 3) & 3) << 7) + ((gm & 15) << 3);
    *(bf16x8*)(XAw + d) = hv;
    if (isL1){
      p0 += __shfl_xor(p0, 1); p0 += __shfl_xor(p0, 2);
      p1 += __shfl_xor(p1, 1); p1 += __shfl_xor(p1, 2);
      if (oct == 0){
        float* op = out + ((size_t)gm * 106 + tstep) * 2;
        atomicAdd(op,     p0);
        atomicAdd(op + 1, p1);
      }
    }
  }
}

// ---------------- launch ----------------
extern "C" void kernel_launch(void* const* d_in, const int* in_sizes, int n_in,
                              void* d_out, int out_size, void* d_ws, size_t ws_size,
                              hipStream_t stream)
{
  (void)in_sizes; (void)n_in; (void)out_size; (void)ws_size;
  const float* x    = (const float*)d_in[0];
  const float* Wih0 = (const float*)d_in[1];
  const float* Whh0 = (const float*)d_in[2];
  const float* bih0 = (const float*)d_in[3];
  const float* bhh0 = (const float*)d_in[4];
  const float* Wih1 = (const float*)d_in[5];
  const float* Whh1 = (const float*)d_in[6];
  const float* bih1 = (const float*)d_in[7];
  const float* bhh1 = (const float*)d_in[8];
  const float* Wfc  = (const float*)d_in[9];
  const float* bfc  = (const float*)d_in[10];
  float* out = (float*)d_out;

  char* ws = (char*)d_ws;
  size_t off = 0;
  auto carve = [&](size_t bytes)->char*{
    char* p = ws + off;
    off += (bytes + 255) & ~(size_t)255;
    return p;
  };
  unsigned short* W0p = (unsigned short*)carve((size_t)4096 * 1024 * 2);
  unsigned short* W1p = (unsigned short*)carve((size_t)4096 * 2048 * 2);
  float*          xb0 = (float*)carve((size_t)512 * 4096 * 4);
  float*          b1r = (float*)carve((size_t)4096 * 4);
  unsigned short* XAp = (unsigned short*)carve((size_t)2 * 512 * 2048 * 2);
  float*          c0  = (float*)carve((size_t)512 * 1024 * 4);
  float*          c1  = (float*)carve((size_t)512 * 1024 * 4);

  k_prep_w<<<dim3(2048), dim3(256), 0, stream>>>(Whh0, Wih1, Whh1, W0p, W1p);
  k_prep_misc<<<dim3(2048), dim3(256), 0, stream>>>(x, Wih0, bih0, bhh0, bih1, bhh1, bfc,
                                                    xb0, b1r, XAp, c0, c1, out);

  const int PS = 512 * 2048;   // parity stride (elements) of XA

  // pipeline head: L0(0) reads XA[1] (zeros), writes h0(0) -> XA[0] panels (cols 0:1024)
  k_lstm_step<<<dim3(256), dim3(512), 0, stream>>>(
    XAp + PS, XAp, W0p, W1p, xb0, b1r, c0, c1, Wfc, out, 0, 1);

  // merged steps: D(tau) = L1(tau) + L0(tau+1); both read XA[tau&1], write XA[(tau&1)^1]
  for (int tau = 0; tau < 105; tau++){
    int p = tau & 1;
    k_lstm_step<<<dim3(512), dim3(512), 0, stream>>>(
      XAp + p * PS, XAp + (p ^ 1) * PS,
      W0p, W1p, xb0, b1r, c0, c1, Wfc, out, tau, 0);
  }

  // pipeline tail: L1(105) reads XA[1] (h0(105), h1(104)), FC pred t=105
  k_lstm_step<<<dim3(256), dim3(512), 0, stream>>>(
    XAp + PS, XAp, W0p, W1p, xb0, b1r, c0, c1, Wfc, out, 105, 2);
}

// Round 15
// 2610.550 us; speedup vs baseline: 1.8243x; 1.8243x over previous
//
#include <hip/hip_runtime.h>
#include <stdint.h>

// ---------------- types / helpers ----------------
typedef short bf16x8 __attribute__((ext_vector_type(8)));
typedef float f32x4  __attribute__((ext_vector_type(4)));

__device__ static inline unsigned short f2bf(float v){
  unsigned x = __float_as_uint(v);
  unsigned r = (x + 0x7fffu + ((x >> 16) & 1u)) >> 16;
  return (unsigned short)r;
}

#define GLOAD16(g, l) \
  __builtin_amdgcn_global_load_lds((const __attribute__((address_space(1))) void*)(g), \
                                   (__attribute__((address_space(3))) void*)(l), 16, 0, 0)

__device__ static inline f32x4 mfma16(bf16x8 a, bf16x8 b, f32x4 c){
  return __builtin_amdgcn_mfma_f32_16x16x32_bf16(a, b, c, 0, 0, 0);
}

// ---------------- prep: weight bf16 round + gate-interleave reorder ----------------
__global__ void k_prep_w(const float* __restrict__ Whh0,
                         const float* __restrict__ Wih1, const float* __restrict__ Whh1,
                         unsigned short* __restrict__ W0hi, unsigned short* __restrict__ W1hi)
{
  const long n0 = (long)4096 * 1024;
  const long n1 = (long)4096 * 2048;
  long stride = (long)gridDim.x * blockDim.x;
  for (long idx = (long)blockIdx.x * blockDim.x + threadIdx.x; idx < n0 + n1; idx += stride){
    if (idx < n0){
      int i = (int)idx;
      int r = i >> 10, k = i & 1023;
      int u = r >> 2, g = r & 3;
      W0hi[i] = f2bf(Whh0[(size_t)(g * 1024 + u) * 1024 + k]);
    } else {
      long i = idx - n0;
      int r = (int)(i >> 11), k = (int)(i & 2047);
      int u = r >> 2, g = r & 3;
      int srow = g * 1024 + u;
      float v = (k < 1024) ? Wih1[(size_t)srow * 1024 + k]
                           : Whh1[(size_t)srow * 1024 + (k - 1024)];
      W1hi[i] = f2bf(v);
    }
  }
}

// ---------------- prep: x-proj+bias (reordered), b1r, zero states, init out ----------------
__global__ void k_prep_misc(const float* __restrict__ x, const float* __restrict__ Wih0,
                            const float* __restrict__ bih0, const float* __restrict__ bhh0,
                            const float* __restrict__ bih1, const float* __restrict__ bhh1,
                            const float* __restrict__ bfc,
                            float* __restrict__ xb0, float* __restrict__ b1r,
                            unsigned short* __restrict__ XAhi,
                            float* __restrict__ c0, float* __restrict__ c1,
                            float* __restrict__ out)
{
  const long NXB = (long)512 * 4096;
  const long NXA = (long)2 * 512 * 2048;
  const long NC  = (long)512 * 1024;
  const long NO  = (long)512 * 106 * 2;
  const long total = NXB + 4096 + NXA + 2 * NC + NO;
  long stride = (long)gridDim.x * blockDim.x;
  for (long idx = (long)blockIdx.x * blockDim.x + threadIdx.x; idx < total; idx += stride){
    long t = idx;
    if (t < NXB){
      int m = (int)(t >> 12), c = (int)(t & 4095);
      int u = c >> 2, g = c & 3;
      int row = g * 1024 + u;
      xb0[t] = x[m * 2 + 0] * Wih0[row * 2 + 0] + x[m * 2 + 1] * Wih0[row * 2 + 1]
             + bih0[row] + bhh0[row];
      continue;
    }
    t -= NXB;
    if (t < 4096){
      int c = (int)t; int u = c >> 2, g = c & 3; int row = g * 1024 + u;
      b1r[c] = bih1[row] + bhh1[row]; continue;
    }
    t -= 4096;
    if (t < NXA){ XAhi[t] = 0; continue; } t -= NXA;
    if (t < NC){ c0[t] = 0.f; continue; } t -= NC;
    if (t < NC){ c1[t] = 0.f; continue; } t -= NC;
    out[t] = bfc[t & 1];
  }
}

// ---------------- merged step kernel: L1(t) and L0(t+1) in one dispatch ----------------
// mode: 0 = merged (512 blocks: [0,256)=L1, [256,512)=L0), 1 = L0-only, 2 = L1-only.
// Per block: tile BM=64, BN=128, BK=64; 8 waves (2x4), wave tile 32x32.
// 3-stage LDS ring (24KB/stage) = 72KB -> 2 blocks/CU in merged mode.
// SINGLE barrier per K-step, CORRECT ordering: STAGE(s+1) -> vmcnt(3) -> barrier ->
// compute(s).  (a) visibility: each wave's own stage-s loads landed before ITS
// barrier arrival, so post-barrier all segments of stage s are in LDS;
// (b) WAR: stage at iter s overwrites slot (s+1)%3, last read at compute(s-2);
// issuing wave has passed BARRIER_{s-1}, reached by every wave only after
// completing compute(s-2); concurrent slow waves are in compute(s-1), a
// different slot. (r14's NaN: vmcnt was AFTER the barrier -> no cross-wave
// visibility. vmcnt-then-barrier is the load-visibility broadcast.)
__global__ __launch_bounds__(512, 4) void k_lstm_step(
  const unsigned short* __restrict__ XAr,
  unsigned short* __restrict__ XAw,
  const unsigned short* __restrict__ W0, const unsigned short* __restrict__ W1,
  const float* __restrict__ xb0, const float* __restrict__ b1r,
  float* __restrict__ c0, float* __restrict__ c1,
  const float* __restrict__ Wfc, float* __restrict__ out,
  int tstep, int mode)
{
  __shared__ char lds[73728];   // 3 stage buffers x 24KB
  const int tid = threadIdx.x;
  const int wid = tid >> 6, lane = tid & 63;

  int L = blockIdx.x;
  bool isL1;
  if (mode == 0){ isL1 = (L < 256); L &= 255; }
  else          { isL1 = (mode == 2); }

  const unsigned short* Whi  = isL1 ? W1 : W0;
  const float*          addv = isL1 ? b1r : xb0;
  const int         addIsMat = isL1 ? 0 : 1;
  float*                cbuf = isL1 ? c1 : c0;
  unsigned short*       Hout = XAw + (isL1 ? 1024 : 0);
  float*                pred = isL1 ? out : nullptr;
  const int               Kw = isL1 ? 2048 : 1024;
  const int               NS = isL1 ? 32 : 16;

  // XCD-grouped mapping: 32 blocks per XCD = 4 N-tiles x 8 M-tiles (per half, bijective)
  int xc = L & 7, j = L >> 3;
  int ntile = xc * 4 + (j & 3);
  int mtile = j >> 2;
  int m0 = mtile * 64, n0 = ntile * 128;
  int wm = wid >> 2, wn = wid & 3;

  // ---- staging state (hoisted): wave owns 3 x 1KB segments of the 24KB stage ----
  int rsub  = lane >> 3;                    // row within 8-row octet
  int col16 = (lane & 7) ^ rsub;            // pre-swizzled 16B-chunk column (involution)
  const unsigned short* gp[3];
  int segByte[3];
  #pragma unroll
  for (int i = 0; i < 3; i++){
    int sg = wid * 3 + i;
    int tb, local;
    const unsigned short* base;
    bool isA;
    if (sg < 8) { tb = 0;    local = sg;     base = XAr; isA = true;  }
    else        { tb = 8192; local = sg - 8; base = Whi; isA = false; }
    int row = local * 8 + rsub;
    gp[i] = isA ? (base + (size_t)(m0 + row) * 2048 + col16 * 8)
                : (base + (size_t)(n0 + row) * Kw   + col16 * 8);
    segByte[i] = tb + local * 1024;
  }

  // ---- compute-side swizzled fragment offsets (stage-invariant) ----
  int offA[2][2], offB[2][2];
  #pragma unroll
  for (int f = 0; f < 2; f++)
    #pragma unroll
    for (int ks = 0; ks < 2; ks++){
      int rowA = wm * 32 + f * 16 + (lane & 15);
      int rowB = wn * 32 + f * 16 + (lane & 15);
      int kb   = ks * 64 + ((lane >> 4) << 4);
      offA[f][ks] = (rowA * 128 + kb) ^ ((rowA & 7) << 4);
      offB[f][ks] = 8192 + ((rowB * 128 + kb) ^ ((rowB & 7) << 4));
    }

  f32x4 acc[2][2];
  #pragma unroll
  for (int a = 0; a < 2; a++)
    #pragma unroll
    for (int b = 0; b < 2; b++)
      acc[a][b] = (f32x4){0.f, 0.f, 0.f, 0.f};

  auto STAGE = [&](int sbuf){
    char* ldsb = lds + sbuf * 24576;
    #pragma unroll
    for (int i = 0; i < 3; i++){
      GLOAD16(gp[i], ldsb + segByte[i]);
      gp[i] += 64;
    }
  };

  STAGE(0);                                 // K-step 0 -> slot 0
  int cur = 0;
  for (int s = 0; s < NS; s++){
    if (s + 1 < NS){
      int nxt = cur + 1; if (nxt >= 3) nxt -= 3;   // K-step s+1 -> slot (s+1)%3
      STAGE(nxt);
      asm volatile("s_waitcnt vmcnt(3)" ::: "memory");  // own stage-s loads landed
    } else {
      asm volatile("s_waitcnt vmcnt(0)" ::: "memory");
    }
    __builtin_amdgcn_s_barrier();          // broadcasts: ALL waves' stage-s data in LDS
    asm volatile("" ::: "memory");

    const char* bb = lds + cur * 24576;
    __builtin_amdgcn_s_setprio(1);
    #pragma unroll
    for (int ks = 0; ks < 2; ks++){
      bf16x8 ah0 = *(const bf16x8*)(bb + offA[0][ks]);
      bf16x8 ah1 = *(const bf16x8*)(bb + offA[1][ks]);
      bf16x8 bh0 = *(const bf16x8*)(bb + offB[0][ks]);
      bf16x8 bh1 = *(const bf16x8*)(bb + offB[1][ks]);
      acc[0][0] = mfma16(ah0, bh0, acc[0][0]);
      acc[0][1] = mfma16(ah0, bh1, acc[0][1]);
      acc[1][0] = mfma16(ah1, bh0, acc[1][0]);
      acc[1][1] = mfma16(ah1, bh1, acc[1][1]);
    }
    __builtin_amdgcn_s_setprio(0);
    asm volatile("" ::: "memory");
    cur += 1; if (cur >= 3) cur -= 3;
  }

  __syncthreads();   // all waves done with ring before LDS reuse as gate buffer

  // ---------- epilogue: acc -> LDS gates [64][129], then pointwise LSTM ----------
  float* gl = (float*)lds;
  #pragma unroll
  for (int fm = 0; fm < 2; fm++)
    #pragma unroll
    for (int fn = 0; fn < 2; fn++)
      #pragma unroll
      for (int r = 0; r < 4; r++){
        int row = wm * 32 + fm * 16 + ((lane >> 4) << 2) + r;
        int col = wn * 32 + fn * 16 + (lane & 15);
        gl[row * 129 + col] = acc[fm][fn][r];
      }
  __syncthreads();

  #pragma unroll
  for (int it = 0; it < 4; it++){
    int u    = tid & 31;
    int rowl = (it << 4) + (tid >> 5);
    int gm = m0 + rowl;
    int gu = (n0 >> 2) + u;
    const float* grow = gl + rowl * 129 + (u << 2);
    float gi = grow[0], gf = grow[1], gg = grow[2], go = grow[3];
    if (addIsMat){
      const float* a = addv + ((size_t)gm << 12) + n0 + (u << 2);
      gi += a[0]; gf += a[1]; gg += a[2]; go += a[3];
    } else {
      const float* a = addv + n0 + (u << 2);
      gi += a[0]; gf += a[1]; gg += a[2]; go += a[3];
    }
    float ii = 1.f / (1.f + expf(-gi));
    float ff = 1.f / (1.f + expf(-gf));
    float g2 = tanhf(gg);
    float oo = 1.f / (1.f + expf(-go));
    size_t ci = ((size_t)gm << 10) + gu;
    float c = ff * cbuf[ci] + ii * g2;
    cbuf[ci] = c;
    float h = oo * tanhf(c);
    size_t hi_idx = ((size_t)gm << 11) + gu;
    Hout[hi_idx] = f2bf(h);
    if (pred){
      float p0 = h * Wfc[gu];
      float p1 = h * Wfc[1024 + gu];
      #pragma unroll
      for (int mm = 16; mm >= 1; mm >>= 1){
        p0 += __shfl_xor(p0, mm);
        p1 += __shfl_xor(p1, mm);
      }
      if ((lane & 31) == 0){
        float* op = pred + ((size_t)gm * 106 + tstep) * 2;
        atomicAdd(op,     p0);
        atomicAdd(op + 1, p1);
      }
    }
  }
}

// ---------------- launch ----------------
extern "C" void kernel_launch(void* const* d_in, const int* in_sizes, int n_in,
                              void* d_out, int out_size, void* d_ws, size_t ws_size,
                              hipStream_t stream)
{
  (void)in_sizes; (void)n_in; (void)out_size; (void)ws_size;
  const float* x    = (const float*)d_in[0];
  const float* Wih0 = (const float*)d_in[1];
  const float* Whh0 = (const float*)d_in[2];
  const float* bih0 = (const float*)d_in[3];
  const float* bhh0 = (const float*)d_in[4];
  const float* Wih1 = (const float*)d_in[5];
  const float* Whh1 = (const float*)d_in[6];
  const float* bih1 = (const float*)d_in[7];
  const float* bhh1 = (const float*)d_in[8];
  const float* Wfc  = (const float*)d_in[9];
  const float* bfc  = (const float*)d_in[10];
  float* out = (float*)d_out;

  char* ws = (char*)d_ws;
  size_t off = 0;
  auto carve = [&](size_t bytes)->char*{
    char* p = ws + off;
    off += (bytes + 255) & ~(size_t)255;
    return p;
  };
  unsigned short* W0hi = (unsigned short*)carve((size_t)4096 * 1024 * 2);
  unsigned short* W1hi = (unsigned short*)carve((size_t)4096 * 2048 * 2);
  float*          xb0  = (float*)carve((size_t)512 * 4096 * 4);
  float*          b1r  = (float*)carve((size_t)4096 * 4);
  unsigned short* XAhi = (unsigned short*)carve((size_t)2 * 512 * 2048 * 2);
  float*          c0   = (float*)carve((size_t)512 * 1024 * 4);
  float*          c1   = (float*)carve((size_t)512 * 1024 * 4);

  k_prep_w<<<dim3(2048), dim3(256), 0, stream>>>(Whh0, Wih1, Whh1, W0hi, W1hi);
  k_prep_misc<<<dim3(2048), dim3(256), 0, stream>>>(x, Wih0, bih0, bhh0, bih1, bhh1, bfc,
                                                    xb0, b1r, XAhi, c0, c1, out);

  const int PS = 512 * 2048;   // parity stride (elements) of XA

  // pipeline head: L0(0) reads XA[1] (zeros), writes h0(0) -> XA[0] cols 0:1024
  k_lstm_step<<<dim3(256), dim3(512), 0, stream>>>(
    XAhi + PS, XAhi, W0hi, W1hi, xb0, b1r, c0, c1, Wfc, out, 0, 1);

  // merged steps: D(tau) = L1(tau) + L0(tau+1); both read XA[tau&1], write XA[(tau&1)^1]
  for (int tau = 0; tau < 105; tau++){
    int p = tau & 1;
    k_lstm_step<<<dim3(512), dim3(512), 0, stream>>>(
      XAhi + p * PS, XAhi + (p ^ 1) * PS,
      W0hi, W1hi, xb0, b1r, c0, c1, Wfc, out, tau, 0);
  }

  // pipeline tail: L1(105) reads XA[1] (h0(105), h1(104)), FC pred t=105
  k_lstm_step<<<dim3(256), dim3(512), 0, stream>>>(
    XAhi + PS, XAhi, W0hi, W1hi, xb0, b1r, c0, c1, Wfc, out, 105, 2);
}